// Round 6
// baseline (638.504 us; speedup 1.0000x reference)
//
#include <hip/hip_runtime.h>
#include <cmath>

// SimplicialAttentionLayer: out = softmax((H Wq)(H Wk)^T * A / sqrt(D)) @ (H Wv)
// N=8192, D=512, fp32. Split-precision bf16 MFMA pipeline.
//  k_scores: virtual-K (K'=1536) m201-style 256x256/BK64/8-wave 4-phase kernel:
//            counted vmcnt(4) (never 0 mid-loop), K-half stage units, slot-XOR
//            swizzle, setprio MFMA clusters. 3-pass precision folded into K'.
//  gemm_bt: template for projections (EPI0) and PV (EPI3, K-split 3-way)

typedef unsigned short u16;
typedef unsigned int   u32;
typedef float f32x4 __attribute__((ext_vector_type(4)));
typedef short s16x8 __attribute__((ext_vector_type(8)));

#define DEVI static __device__ __forceinline__

DEVI u16 f2bf(float x) { u32 u = __float_as_uint(x); u32 r = u + 0x7fffu + ((u >> 16) & 1u); return (u16)(r >> 16); }
DEVI float bf2f(u16 b) { return __uint_as_float((u32)b << 16); }

DEVI f32x4 mm_bf16(s16x8 a, s16x8 b, f32x4 c) {
  return __builtin_amdgcn_mfma_f32_16x16x32_bf16(a, b, c, 0, 0, 0);
}

// async global->LDS, 16 B per lane (dest: wave-uniform base + lane*16)
DEVI void gll16(const u16* g, u16* l) {
  __builtin_amdgcn_global_load_lds((const __attribute__((address_space(1))) void*)g,
                                   (__attribute__((address_space(3))) void*)l, 16, 0, 0);
}

// scale 8 packed bf16 by f, round-nearest, repack via v_perm
DEVI uint4 scaleP(uint4 v, float f) {
  u32* w = (u32*)&v;
#pragma unroll
  for (int j = 0; j < 4; j++) {
    u32 lo = __float_as_uint(__uint_as_float(w[j] << 16) * f) + 0x8000u;
    u32 hi = __float_as_uint(__uint_as_float(w[j] & 0xffff0000u) * f) + 0x8000u;
    w[j] = __builtin_amdgcn_perm(hi, lo, 0x07060302);
  }
  return v;
}

// ---------------- elementwise prep kernels ----------------

__global__ void k_split(const float* __restrict__ X, u16* __restrict__ Xhi, u16* __restrict__ Xlo, int n4) {
  int i = blockIdx.x * 256 + threadIdx.x;
  if (i >= n4) return;
  float4 v = ((const float4*)X)[i];
  u16 h0 = f2bf(v.x), h1 = f2bf(v.y), h2 = f2bf(v.z), h3 = f2bf(v.w);
  u16 l0 = f2bf(v.x - bf2f(h0)), l1 = f2bf(v.y - bf2f(h1));
  u16 l2 = f2bf(v.z - bf2f(h2)), l3 = f2bf(v.w - bf2f(h3));
  ((uint2*)Xhi)[i] = make_uint2((u32)h0 | ((u32)h1 << 16), (u32)h2 | ((u32)h3 << 16));
  ((uint2*)Xlo)[i] = make_uint2((u32)l0 | ((u32)l1 << 16), (u32)l2 | ((u32)l3 << 16));
}

__global__ void k_prepW(const float* __restrict__ W0, const float* __restrict__ W1, const float* __restrict__ W2,
                        u16* __restrict__ Thi, u16* __restrict__ Tlo) {
  int idx = blockIdx.x * 256 + threadIdx.x;
  if (idx >= 3 * 512 * 512) return;
  int w = idx >> 18, n = (idx >> 9) & 511, k = idx & 511;
  const float* W = (w == 0) ? W0 : (w == 1) ? W1 : W2;
  float v = W[k * 512 + n];
  u16 h = f2bf(v);
  Thi[idx] = h;
  Tlo[idx] = f2bf(v - bf2f(h));
}

__global__ void k_transpose(const u16* __restrict__ in, u16* __restrict__ out, int R, int C) {
  __shared__ u16 t[64][72];
  const int rb = blockIdx.x * 64, cb = blockIdx.y * 64;
  const int r = threadIdx.x >> 2, c4 = (threadIdx.x & 3) * 16;
  const u16* src = in + (size_t)(rb + r) * C + cb + c4;
  *(uint4*)&t[r][c4] = *(const uint4*)src;
  *(uint4*)&t[r][c4 + 8] = *(const uint4*)(src + 8);
  __syncthreads();
  u16 v[16];
#pragma unroll
  for (int j = 0; j < 16; j++) v[j] = t[c4 + j][r];
  uint4 o0, o1;
  o0.x = v[0] | ((u32)v[1] << 16); o0.y = v[2] | ((u32)v[3] << 16);
  o0.z = v[4] | ((u32)v[5] << 16); o0.w = v[6] | ((u32)v[7] << 16);
  o1.x = v[8] | ((u32)v[9] << 16); o1.y = v[10] | ((u32)v[11] << 16);
  o1.z = v[12] | ((u32)v[13] << 16); o1.w = v[14] | ((u32)v[15] << 16);
  u16* dst = out + (size_t)(cb + r) * R + rb + c4;
  *(uint4*)dst = o0;
  *(uint4*)(dst + 8) = o1;
}

// ---------------- scores: virtual-K 256x256 / BK=64 / 8 waves / 4 phases ----------------
// S^T tile [256 kv][256 q] = HK-tile @ HQ-tile^T over virtual K'=1536:
// virtual 8-elem chunk c: term c%3 in {Ah*Bh, Ah*Bl, Al*Bh} of phys chunk c/3
// (term selected in the per-lane gll SOURCE address; L2 absorbs the re-read).
// LDS per buf: A[2kh][256][32] | B[2kh][256][32] (64 KB); dbuf = 128 KB.
// Swizzle: 16B-slot ^= (row&3), both gll-source-chunk and ds_read sides.
// Stage unit = one operand x k-half (16 KB = 2 gll). Per tile: issue A0@ph0,
// B0@ph1, A1@ph2, B1@ph3 for t+1; vmcnt(4) at ph1/ph3 (counted, never 0 mid-loop).

#define SC_RD_A(MO, KH, CB) \
  _Pragma("unroll") for (int m = 0; m < 4; m++) \
    a[m] = *(const s16x8*)(lds + (CB) + (KH) * 8192 + aBase + ((MO) + m) * 512);
#define SC_RD_B(KH, CB) \
  _Pragma("unroll") for (int nt = 0; nt < 4; nt++) \
    b[nt] = *(const s16x8*)(lds + (CB) + (KH) * 8192 + bBase + nt * 512);
#define SC_MFMA(MO) \
  __builtin_amdgcn_s_setprio(1); \
  _Pragma("unroll") for (int nt = 0; nt < 4; nt++) { \
    _Pragma("unroll") for (int m = 0; m < 4; m++) \
      acc[(MO) + m][nt] = mm_bf16(a[m], b[nt], acc[(MO) + m][nt]); \
  } \
  __builtin_amdgcn_s_setprio(0);
#define SC_WAIT_LGKM \
  asm volatile("s_waitcnt lgkmcnt(0)" ::: "memory"); \
  __builtin_amdgcn_sched_barrier(0);

__launch_bounds__(512, 1)
__global__ void k_scores(const u16* __restrict__ Ahi, const u16* __restrict__ Alo,
                         const u16* __restrict__ Bhi, const u16* __restrict__ Blo,
                         const float* __restrict__ Adj, float* __restrict__ mC,
                         float* __restrict__ lC, u16* __restrict__ Pout, float scale)
{
  constexpr int NN = 8192;
  constexpr int NT = 24;                     // K' = 1536 = NT*64
  __shared__ __align__(16) u16 lds[65536];   // 128 KB

  const int tid = threadIdx.x, lane = tid & 63, wid = tid >> 6;
  const int wm = wid >> 2, wn = wid & 3;     // kv-half x q-quarter
  const int lr = lane & 15, lk = lane >> 4;
  const int mbase = blockIdx.x * 256, nbase = blockIdx.y * 256;

  // frag read bases (u16 idx; swizzle: 16B-slot ^= row&3, row&3 == lr&3)
  const int aBase = (wm * 128 + lr) * 32 + (lk ^ (lr & 3)) * 8;
  const int bBase = 16384 + (wn * 64 + lr) * 32 + (lk ^ (lr & 3)) * 8;

  // staging thread decomposition
  const int srow4 = tid >> 2;                       // 128 rows per gll
  const int schnk = (tid & 3) ^ ((tid >> 2) & 3);   // pre-swizzled logical chunk

  auto STAGE = [&](int isB, int kh, int t1, int nb) {
    const int vch = t1 * 8 + kh * 4 + schnk;        // virtual chunk index
    const int pch = vch / 3, term = vch - pch * 3;  // phys chunk + term
    const u16* src = isB ? ((term == 1) ? Blo : Bhi)
                         : ((term == 2) ? Alo : Ahi);
    const int rb = (isB ? nbase : mbase) + srow4;
    u16* dst = lds + nb + isB * 16384 + kh * 8192 + tid * 8;
#pragma unroll
    for (int g = 0; g < 2; ++g)
      gll16(src + (size_t)(rb + g * 128) * 512 + pch * 8, dst + g * 4096);
  };

  // prologue: tile 0 units into buf0, counted wait on first two
  STAGE(0, 0, 0, 0); STAGE(1, 0, 0, 0); STAGE(0, 1, 0, 0); STAGE(1, 1, 0, 0);
  asm volatile("s_waitcnt vmcnt(4)" ::: "memory");
  __builtin_amdgcn_s_barrier();

  f32x4 acc[8][4] = {};

  for (int t = 0; t < NT; ++t) {
    const int cb = (t & 1) * 32768, nb = ((t + 1) & 1) * 32768;
    const bool more = (t + 1 < NT);
    s16x8 a[4], b[4];

    // ---- ph0: B(kh0) + A(mt0-3,kh0); stage A-kh0(t+1)
    SC_RD_B(0, cb)
    SC_RD_A(0, 0, cb)
    if (more) STAGE(0, 0, t + 1, nb);
    __builtin_amdgcn_s_barrier();
    SC_WAIT_LGKM
    SC_MFMA(0)
    __builtin_amdgcn_s_barrier();

    // ---- ph1: A(mt4-7,kh0); stage B-kh0(t+1); counted wait for {A-kh1,B-kh1}(t)
    SC_RD_A(4, 0, cb)
    if (more) STAGE(1, 0, t + 1, nb);
    __builtin_amdgcn_s_barrier();
    SC_WAIT_LGKM
    SC_MFMA(4)
    if (more) asm volatile("s_waitcnt vmcnt(4)" ::: "memory");
    else      asm volatile("s_waitcnt vmcnt(0)" ::: "memory");
    __builtin_amdgcn_s_barrier();

    // ---- ph2: B(kh1) + A(mt0-3,kh1); stage A-kh1(t+1)
    SC_RD_B(1, cb)
    SC_RD_A(0, 1, cb)
    if (more) STAGE(0, 1, t + 1, nb);
    __builtin_amdgcn_s_barrier();
    SC_WAIT_LGKM
    SC_MFMA(0)
    __builtin_amdgcn_s_barrier();

    // ---- ph3: A(mt4-7,kh1); stage B-kh1(t+1); counted wait for {A-kh0,B-kh0}(t+1)
    SC_RD_A(4, 1, cb)
    if (more) STAGE(1, 1, t + 1, nb);
    __builtin_amdgcn_s_barrier();
    SC_WAIT_LGKM
    SC_MFMA(4)
    if (more) asm volatile("s_waitcnt vmcnt(4)" ::: "memory");
    __builtin_amdgcn_s_barrier();
  }

  // ---- epilogue: mask*scale, per-wave chunk softmax (chunk = wave's 128 kv), P' ----
  const int c = blockIdx.x * 2 + wm;
#pragma unroll
  for (int nt = 0; nt < 4; nt++) {
    const int q_l = wn * 64 + nt * 16 + lr;
    const float* arow = Adj + (size_t)(nbase + q_l) * NN + mbase + wm * 128 + lk * 4;
    float4 a4[8];
#pragma unroll
    for (int mt = 0; mt < 8; mt++) a4[mt] = *(const float4*)(arow + mt * 16);
    float mx = -3.4e38f;
#pragma unroll
    for (int mt = 0; mt < 8; mt++)
#pragma unroll
      for (int r = 0; r < 4; r++) {
        float s = acc[mt][nt][r] * ((const float*)&a4[mt])[r] * scale;
        acc[mt][nt][r] = s;
        mx = fmaxf(mx, s);
      }
    mx = fmaxf(mx, __shfl_xor(mx, 16));
    mx = fmaxf(mx, __shfl_xor(mx, 32));
    float sm = 0.f;
#pragma unroll
    for (int mt = 0; mt < 8; mt++)
#pragma unroll
      for (int r = 0; r < 4; r++) {
        float p = __expf(acc[mt][nt][r] - mx);
        acc[mt][nt][r] = p;
        sm += p;
      }
    sm += __shfl_xor(sm, 16);
    sm += __shfl_xor(sm, 32);
    if (lane < 16) {
      mC[(size_t)c * NN + nbase + wn * 64 + nt * 16 + lane] = mx;
      lC[(size_t)c * NN + nbase + wn * 64 + nt * 16 + lane] = sm;
    }
  }

  // bounce P' [256 q][256 kv] through LDS (kv XOR-swizzled), coalesced global write
  __builtin_amdgcn_s_barrier();
  u16* pb = lds;
#pragma unroll
  for (int nt = 0; nt < 4; nt++) {
    const int q_l = wn * 64 + nt * 16 + lr;
    const int qsw = (q_l & 7) << 3;
#pragma unroll
    for (int mt = 0; mt < 8; mt++) {
      const int kv = wm * 128 + mt * 16 + lk * 4;
      u32 u0 = (u32)f2bf(acc[mt][nt][0]) | ((u32)f2bf(acc[mt][nt][1]) << 16);
      u32 u1 = (u32)f2bf(acc[mt][nt][2]) | ((u32)f2bf(acc[mt][nt][3]) << 16);
      *(uint2*)&pb[q_l * 256 + (kv ^ qsw)] = make_uint2(u0, u1);
    }
  }
  __syncthreads();
  {
    const int q_r = tid >> 1, half = tid & 1;
    const int qsw = (q_r & 7) << 3;
    u16* dst = Pout + (size_t)(nbase + q_r) * NN + mbase + half * 128;
#pragma unroll
    for (int i = 0; i < 16; i++) {
      const int kv8 = (half * 128 + i * 8) ^ qsw;
      *(uint4*)(dst + i * 8) = *(const uint4*)&pb[q_r * 256 + kv8];
    }
  }
}

// ---------------- GEMM template: C = A @ B^T (projections & PV) ----------------
// EPI: 0 = write hi/lo bf16 C ; 3 = fp32 C with F-scaled A staging
// PASSES: 3 = AhBh+AhBl+AlBh ; 2 = AhBh+AhBl
// FUSEW: blockIdx.y packs {w = y>>2, ny = y&3}
// KSPLIT: K split across blockIdx.z; z>0 -> Cf1/Cf2 partials

template<int EPI, int PASSES, int FUSEW, int KSPLIT>
__launch_bounds__(256, 4)
__global__ void gemm_bt(const u16* __restrict__ Ahi, const u16* __restrict__ Alo,
                        const u16* __restrict__ Bhi, const u16* __restrict__ Blo,
                        int M, int N, int K,
                        float* __restrict__ Cf, float* __restrict__ Cf1, float* __restrict__ Cf2,
                        u16* __restrict__ C0, u16* __restrict__ C1,
                        const float* __restrict__ Fsc)
{
  constexpr int BUF = 128 * 40;
  constexpr int NBUF = (PASSES == 3) ? 4 : 3;
  __shared__ __align__(16) u16 lds[BUF * NBUF];

  u16* sAh = lds;
  u16* sAl = lds + BUF;
  u16* sBh = lds + ((PASSES == 3) ? 2 : 1) * BUF;
  u16* sBl = lds + ((PASSES == 3) ? 3 : 2) * BUF;

  const int tid = threadIdx.x, lane = tid & 63, wid = tid >> 6;
  const int wm = wid & 1, wn = wid >> 1;
  const int lr = lane & 15, lk = lane >> 4;
  const int mbase = blockIdx.x * 128;
  int nbase;
  const u16 *bhp = Bhi, *blp = Blo;
  u16 *c0 = C0, *c1 = C1;
  if constexpr (FUSEW) {
    const int w = blockIdx.y >> 2;
    nbase = (blockIdx.y & 3) * 128;
    bhp += (size_t)w * 262144;  blp += (size_t)w * 262144;
    c0  += (size_t)w * 4194304; c1  += (size_t)w * 4194304;
  } else {
    nbase = blockIdx.y * 128;
  }
  const int srow = tid >> 1, shalf = tid & 1;
  const size_t Ks = (size_t)K;

  int kbeg = 0, kend = K;
  if constexpr (KSPLIT > 1) {
    const int steps = K >> 5, bz = blockIdx.z;
    kbeg = ((steps * bz) / KSPLIT) << 5;
    kend = ((steps * (bz + 1)) / KSPLIT) << 5;
  }

  f32x4 acc[4][4] = {};

  for (int kt = kbeg; kt < kend; kt += 32) {
    const size_t aoff = (size_t)(mbase + srow) * Ks + kt + shalf * 16;
    const size_t boff = (size_t)(nbase + srow) * Ks + kt + shalf * 16;
    uint4 vah0 = *(const uint4*)(Ahi + aoff), vah1 = *(const uint4*)(Ahi + aoff + 8);
    uint4 vbh0 = *(const uint4*)(bhp + boff), vbh1 = *(const uint4*)(bhp + boff + 8);
    uint4 val0, val1, vbl0, vbl1;
    if constexpr (PASSES == 3) { val0 = *(const uint4*)(Alo + aoff); val1 = *(const uint4*)(Alo + aoff + 8); }
    vbl0 = *(const uint4*)(blp + boff); vbl1 = *(const uint4*)(blp + boff + 8);
    if constexpr (EPI == 3) {
      const float f = Fsc[((size_t)(kt >> 7) << 13) + mbase + srow];
      vah0 = scaleP(vah0, f); vah1 = scaleP(vah1, f);
    }
    __syncthreads();
    const int so = srow * 40 + shalf * 16;
    *(uint4*)(sAh + so) = vah0; *(uint4*)(sAh + so + 8) = vah1;
    *(uint4*)(sBh + so) = vbh0; *(uint4*)(sBh + so + 8) = vbh1;
    if constexpr (PASSES == 3) { *(uint4*)(sAl + so) = val0; *(uint4*)(sAl + so + 8) = val1; }
    *(uint4*)(sBl + so) = vbl0; *(uint4*)(sBl + so + 8) = vbl1;
    __syncthreads();

    s16x8 ah[4], bh[4], al[4], bl[4];
#pragma unroll
    for (int t = 0; t < 4; t++) {
      ah[t] = *(const s16x8*)(sAh + (wm * 64 + t * 16 + lr) * 40 + lk * 8);
      bh[t] = *(const s16x8*)(sBh + (wn * 64 + t * 16 + lr) * 40 + lk * 8);
      if constexpr (PASSES == 3) al[t] = *(const s16x8*)(sAl + (wm * 64 + t * 16 + lr) * 40 + lk * 8);
      bl[t] = *(const s16x8*)(sBl + (wn * 64 + t * 16 + lr) * 40 + lk * 8);
    }
#pragma unroll
    for (int mt = 0; mt < 4; mt++)
#pragma unroll
      for (int nt = 0; nt < 4; nt++) {
        acc[mt][nt] = mm_bf16(ah[mt], bh[nt], acc[mt][nt]);
        acc[mt][nt] = mm_bf16(ah[mt], bl[nt], acc[mt][nt]);
        if constexpr (PASSES == 3) acc[mt][nt] = mm_bf16(al[mt], bh[nt], acc[mt][nt]);
      }
  }

  float* cfp = Cf;
  if constexpr (KSPLIT > 1) {
    if (blockIdx.z == 1) cfp = Cf1;
    else if (blockIdx.z == 2) cfp = Cf2;
  }
#pragma unroll
  for (int mt = 0; mt < 4; mt++)
#pragma unroll
    for (int nt = 0; nt < 4; nt++) {
      const int grow = mbase + wm * 64 + mt * 16 + lk * 4;
      const int gcol = nbase + wn * 64 + nt * 16 + lr;
#pragma unroll
      for (int r = 0; r < 4; r++) {
        float c = acc[mt][nt][r];
        size_t o = (size_t)(grow + r) * N + gcol;
        if constexpr (EPI == 0) {
          u16 h = f2bf(c);
          c0[o] = h;
          c1[o] = f2bf(c - bf2f(h));
        } else {
          cfp[o] = c;
        }
      }
    }
}

// ---------------- softmax cross-chunk reduce ----------------

__global__ void k_reduce(const float* __restrict__ mC, const float* __restrict__ lC, float* __restrict__ F,
                         int NQ, int NC) {
  const int q = blockIdx.x * 256 + threadIdx.x;
  if (q >= NQ) return;
  float mf = -3.4e38f;
  for (int c = 0; c < NC; c++) mf = fmaxf(mf, mC[(size_t)c * NQ + q]);
  float L = 0.f;
  for (int c = 0; c < NC; c++) L += lC[(size_t)c * NQ + q] * __expf(mC[(size_t)c * NQ + q] - mf);
  const float inv = 1.0f / L;
  for (int c = 0; c < NC; c++) F[(size_t)c * NQ + q] = __expf(mC[(size_t)c * NQ + q] - mf) * inv;
}

__global__ void k_sumout(float* __restrict__ out, const float* __restrict__ p1, const float* __restrict__ p2, int n4) {
  int i = blockIdx.x * 256 + threadIdx.x;
  if (i >= n4) return;
  float4 o = ((const float4*)out)[i];
  float4 a = ((const float4*)p1)[i];
  float4 b = ((const float4*)p2)[i];
  o.x += a.x + b.x; o.y += a.y + b.y; o.z += a.z + b.z; o.w += a.w + b.w;
  ((float4*)out)[i] = o;
}

// ---------------- launcher ----------------

extern "C" void kernel_launch(void* const* d_in, const int* in_sizes, int n_in,
                              void* d_out, int out_size, void* d_ws, size_t ws_size,
                              hipStream_t stream) {
  const float* H  = (const float*)d_in[0];
  const float* Aj = (const float*)d_in[1];
  const float* Wq = (const float*)d_in[2];
  const float* Wk = (const float*)d_in[3];
  const float* Wv = (const float*)d_in[4];
  float* out = (float*)d_out;
  const int NN = 8192, DD = 512;

  char* ws = (char*)d_ws;
  size_t off = 0;
  auto alloc = [&](size_t bytes) -> void* {
    void* p = ws + off;
    off += (bytes + 255) & ~(size_t)255;
    return p;
  };
  u16* Pbuf  = (u16*)alloc((size_t)NN * NN * 2);           // 128 MB
  u16* Hhi   = (u16*)alloc((size_t)NN * DD * 2);
  u16* Hlo   = (u16*)alloc((size_t)NN * DD * 2);
  u16* WThi  = (u16*)alloc((size_t)3 * DD * DD * 2);
  u16* WTlo  = (u16*)alloc((size_t)3 * DD * DD * 2);
  u16* PRhi  = (u16*)alloc((size_t)3 * NN * DD * 2);       // [HQ|HK|HV] hi
  u16* PRlo  = (u16*)alloc((size_t)3 * NN * DD * 2);
  u16* HVthi = (u16*)alloc((size_t)NN * DD * 2);
  u16* HVtlo = (u16*)alloc((size_t)NN * DD * 2);
  float* mC  = (float*)alloc((size_t)64 * NN * 4);
  float* lC  = (float*)alloc((size_t)64 * NN * 4);
  float* Ft  = (float*)alloc((size_t)64 * NN * 4);
  if (off > ws_size) return;  // workspace too small -> visible failure

  u16* HQhi = PRhi;                 u16* HQlo = PRlo;
  u16* HKhi = PRhi + (size_t)NN*DD; u16* HKlo = PRlo + (size_t)NN*DD;
  u16* HVhi = PRhi + (size_t)2*NN*DD; u16* HVlo = PRlo + (size_t)2*NN*DD;

  // K-split partials for PV GEMM: alias the dead region (Hhi.. is dead by then)
  float* part1 = (float*)Hhi;
  float* part2 = (float*)((char*)Hhi + (size_t)NN * DD * 4);

  const float scl = 1.0f / sqrtf((float)DD);

  k_split<<<4096, 256, 0, stream>>>(H, Hhi, Hlo, NN * DD / 4);
  k_prepW<<<3072, 256, 0, stream>>>(Wq, Wk, Wv, WThi, WTlo);

  dim3 gP(64, 12);
  gemm_bt<0, 3, 1, 1><<<gP, 256, 0, stream>>>(Hhi, Hlo, WThi, WTlo, NN, DD, DD,
                                              nullptr, nullptr, nullptr, PRhi, PRlo, nullptr);

  dim3 gT(128, 8);
  k_transpose<<<gT, 256, 0, stream>>>(HVhi, HVthi, NN, DD);
  k_transpose<<<gT, 256, 0, stream>>>(HVlo, HVtlo, NN, DD);

  dim3 gS(32, 32);
  k_scores<<<gS, 512, 0, stream>>>(HKhi, HKlo, HQhi, HQlo, Aj, mC, lC, Pbuf, scl);

  k_reduce<<<32, 256, 0, stream>>>(mC, lC, Ft, NN, 64);

  dim3 gO(64, 4, 3);
  gemm_bt<3, 2, 0, 3><<<gO, 256, 0, stream>>>(Pbuf, nullptr, HVthi, HVtlo, NN, DD, NN,
                                              out, part1, part2, nullptr, nullptr, Ft);

  k_sumout<<<4096, 256, 0, stream>>>(out, part1, part2, NN * DD / 4);
}

// Round 7
// 498.356 us; speedup vs baseline: 1.2812x; 1.2812x over previous
//
#include <hip/hip_runtime.h>
#include <cmath>

// SimplicialAttentionLayer: out = softmax((H Wq)(H Wk)^T * A / sqrt(D)) @ (H Wv)
// N=8192, D=512, fp32. Split-precision bf16 MFMA pipeline.
//  k_split: H -> hi/lo bf16 ; k_prepW: W^T hi/lo
//  gemm_bt<0,3,1,1>: fused 3-projection GEMM -> HQ/HK/HV hi/lo
//  k_transpose: HVhi -> HVt (lo term of V dropped in PV: |err| <= 2^-9*|V| ~ 0.1)
//  gemm_bt<2,3,0,1>: scores 3-pass (R3-proven structure); epilogue: mask+scale,
//                    chunk max/sum, P'=exp(s-m_c) bf16 ; mC/lC tables
//  k_reduce: F[c][q] = exp(m_c - m_fin)/L
//  gemm_bt<3,1,0,3>: out = (P'*F) @ HVt^T, 1-pass, F folded into A-staging,
//                    K split 3-way across blockIdx.z (partials in dead ws)
//  k_sumout: out += partial1 + partial2

typedef unsigned short u16;
typedef unsigned int   u32;
typedef float f32x4 __attribute__((ext_vector_type(4)));
typedef short s16x8 __attribute__((ext_vector_type(8)));

#define DEVI static __device__ __forceinline__

DEVI u16 f2bf(float x) { u32 u = __float_as_uint(x); u32 r = u + 0x7fffu + ((u >> 16) & 1u); return (u16)(r >> 16); }
DEVI float bf2f(u16 b) { return __uint_as_float((u32)b << 16); }

DEVI f32x4 mm_bf16(s16x8 a, s16x8 b, f32x4 c) {
  return __builtin_amdgcn_mfma_f32_16x16x32_bf16(a, b, c, 0, 0, 0);
}

// scale 8 packed bf16 by f, round-nearest, repack via v_perm
DEVI uint4 scaleP(uint4 v, float f) {
  u32* w = (u32*)&v;
#pragma unroll
  for (int j = 0; j < 4; j++) {
    u32 lo = __float_as_uint(__uint_as_float(w[j] << 16) * f) + 0x8000u;
    u32 hi = __float_as_uint(__uint_as_float(w[j] & 0xffff0000u) * f) + 0x8000u;
    w[j] = __builtin_amdgcn_perm(hi, lo, 0x07060302);
  }
  return v;
}

// ---------------- elementwise prep kernels ----------------

__global__ void k_split(const float* __restrict__ X, u16* __restrict__ Xhi, u16* __restrict__ Xlo, int n4) {
  int i = blockIdx.x * 256 + threadIdx.x;
  if (i >= n4) return;
  float4 v = ((const float4*)X)[i];
  u16 h0 = f2bf(v.x), h1 = f2bf(v.y), h2 = f2bf(v.z), h3 = f2bf(v.w);
  u16 l0 = f2bf(v.x - bf2f(h0)), l1 = f2bf(v.y - bf2f(h1));
  u16 l2 = f2bf(v.z - bf2f(h2)), l3 = f2bf(v.w - bf2f(h3));
  ((uint2*)Xhi)[i] = make_uint2((u32)h0 | ((u32)h1 << 16), (u32)h2 | ((u32)h3 << 16));
  ((uint2*)Xlo)[i] = make_uint2((u32)l0 | ((u32)l1 << 16), (u32)l2 | ((u32)l3 << 16));
}

__global__ void k_prepW(const float* __restrict__ W0, const float* __restrict__ W1, const float* __restrict__ W2,
                        u16* __restrict__ Thi, u16* __restrict__ Tlo) {
  int idx = blockIdx.x * 256 + threadIdx.x;
  if (idx >= 3 * 512 * 512) return;
  int w = idx >> 18, n = (idx >> 9) & 511, k = idx & 511;
  const float* W = (w == 0) ? W0 : (w == 1) ? W1 : W2;
  float v = W[k * 512 + n];
  u16 h = f2bf(v);
  Thi[idx] = h;
  Tlo[idx] = f2bf(v - bf2f(h));
}

__global__ void k_transpose(const u16* __restrict__ in, u16* __restrict__ out, int R, int C) {
  __shared__ u16 t[64][72];
  const int rb = blockIdx.x * 64, cb = blockIdx.y * 64;
  const int r = threadIdx.x >> 2, c4 = (threadIdx.x & 3) * 16;
  const u16* src = in + (size_t)(rb + r) * C + cb + c4;
  *(uint4*)&t[r][c4] = *(const uint4*)src;
  *(uint4*)&t[r][c4 + 8] = *(const uint4*)(src + 8);
  __syncthreads();
  u16 v[16];
#pragma unroll
  for (int j = 0; j < 16; j++) v[j] = t[c4 + j][r];
  uint4 o0, o1;
  o0.x = v[0] | ((u32)v[1] << 16); o0.y = v[2] | ((u32)v[3] << 16);
  o0.z = v[4] | ((u32)v[5] << 16); o0.w = v[6] | ((u32)v[7] << 16);
  o1.x = v[8] | ((u32)v[9] << 16); o1.y = v[10] | ((u32)v[11] << 16);
  o1.z = v[12] | ((u32)v[13] << 16); o1.w = v[14] | ((u32)v[15] << 16);
  u16* dst = out + (size_t)(cb + r) * R + rb + c4;
  *(uint4*)dst = o0;
  *(uint4*)(dst + 8) = o1;
}

// ---------------- GEMM template: C = A @ B^T, operands [rows][K] row-major ----------------
// EPI: 0 = write hi/lo bf16 C ; 2 = scores epilogue ; 3 = fp32 C with F-scaled A staging
// PASSES: 3 = AhBh+AhBl+AlBh ; 2 = AhBh+AhBl ; 1 = AhBh
// FUSEW: blockIdx.y packs {w = y>>2, ny = y&3}; B/C get per-w offsets
// KSPLIT: K-range split across blockIdx.z; z>0 writes Cf1/Cf2 partials (EPI==3 only)

template<int EPI, int PASSES, int FUSEW, int KSPLIT>
__launch_bounds__(256, 4)
__global__ void gemm_bt(const u16* __restrict__ Ahi, const u16* __restrict__ Alo,
                        const u16* __restrict__ Bhi, const u16* __restrict__ Blo,
                        int M, int N, int K,
                        float* __restrict__ Cf, float* __restrict__ Cf1, float* __restrict__ Cf2,
                        u16* __restrict__ C0, u16* __restrict__ C1,
                        const float* __restrict__ Adj, float* __restrict__ mC, float* __restrict__ lC,
                        u16* __restrict__ Pout, const float* __restrict__ Fsc, float scale)
{
  constexpr int BUF = 128 * 40;  // [128 rows][32 k + 8 pad] u16 (80 B rows)
  constexpr int NBUF = (PASSES == 3) ? 4 : (PASSES == 2 ? 3 : 2);
  __shared__ __align__(16) u16 lds[BUF * NBUF];

  u16* sAh = lds;
  u16* sAl = lds + BUF;                                   // PASSES==3 only
  u16* sBh = lds + ((PASSES == 3) ? 2 : 1) * BUF;
  u16* sBl = lds + ((PASSES == 3) ? 3 : 2) * BUF;         // PASSES>=2 only

  const int tid = threadIdx.x, lane = tid & 63, wid = tid >> 6;
  const int wm = wid & 1, wn = wid >> 1;
  const int lr = lane & 15, lk = lane >> 4;
  const int mbase = blockIdx.x * 128;
  int nbase;
  const u16 *bhp = Bhi, *blp = Blo;
  u16 *c0 = C0, *c1 = C1;
  if constexpr (FUSEW) {
    const int w = blockIdx.y >> 2;
    nbase = (blockIdx.y & 3) * 128;
    bhp += (size_t)w * 262144;  blp += (size_t)w * 262144;
    c0  += (size_t)w * 4194304; c1  += (size_t)w * 4194304;
  } else {
    nbase = blockIdx.y * 128;
  }
  const int srow = tid >> 1, shalf = tid & 1;
  const size_t Ks = (size_t)K;

  int kbeg = 0, kend = K;
  if constexpr (KSPLIT > 1) {
    const int steps = K >> 5, bz = blockIdx.z;
    kbeg = ((steps * bz) / KSPLIT) << 5;
    kend = ((steps * (bz + 1)) / KSPLIT) << 5;
  }

  f32x4 acc[4][4] = {};

  for (int kt = kbeg; kt < kend; kt += 32) {
    const size_t aoff = (size_t)(mbase + srow) * Ks + kt + shalf * 16;
    const size_t boff = (size_t)(nbase + srow) * Ks + kt + shalf * 16;
    uint4 vah0 = *(const uint4*)(Ahi + aoff), vah1 = *(const uint4*)(Ahi + aoff + 8);
    uint4 vbh0 = *(const uint4*)(bhp + boff), vbh1 = *(const uint4*)(bhp + boff + 8);
    uint4 val0, val1, vbl0, vbl1;
    if constexpr (PASSES == 3) { val0 = *(const uint4*)(Alo + aoff); val1 = *(const uint4*)(Alo + aoff + 8); }
    if constexpr (PASSES >= 2) { vbl0 = *(const uint4*)(blp + boff); vbl1 = *(const uint4*)(blp + boff + 8); }
    if constexpr (EPI == 3) {  // fold softmax fixup F into P staging
      const float f = Fsc[((size_t)(kt >> 7) << 13) + mbase + srow];
      vah0 = scaleP(vah0, f); vah1 = scaleP(vah1, f);
    }
    __syncthreads();
    const int so = srow * 40 + shalf * 16;
    *(uint4*)(sAh + so) = vah0; *(uint4*)(sAh + so + 8) = vah1;
    *(uint4*)(sBh + so) = vbh0; *(uint4*)(sBh + so + 8) = vbh1;
    if constexpr (PASSES == 3) { *(uint4*)(sAl + so) = val0; *(uint4*)(sAl + so + 8) = val1; }
    if constexpr (PASSES >= 2) { *(uint4*)(sBl + so) = vbl0; *(uint4*)(sBl + so + 8) = vbl1; }
    __syncthreads();

    s16x8 ah[4], bh[4], al[4], bl[4];
#pragma unroll
    for (int t = 0; t < 4; t++) {
      ah[t] = *(const s16x8*)(sAh + (wm * 64 + t * 16 + lr) * 40 + lk * 8);
      bh[t] = *(const s16x8*)(sBh + (wn * 64 + t * 16 + lr) * 40 + lk * 8);
      if constexpr (PASSES == 3) al[t] = *(const s16x8*)(sAl + (wm * 64 + t * 16 + lr) * 40 + lk * 8);
      if constexpr (PASSES >= 2) bl[t] = *(const s16x8*)(sBl + (wn * 64 + t * 16 + lr) * 40 + lk * 8);
    }
#pragma unroll
    for (int mt = 0; mt < 4; mt++)
#pragma unroll
      for (int nt = 0; nt < 4; nt++) {
        acc[mt][nt] = mm_bf16(ah[mt], bh[nt], acc[mt][nt]);
        if constexpr (PASSES >= 2) acc[mt][nt] = mm_bf16(ah[mt], bl[nt], acc[mt][nt]);
        if constexpr (PASSES == 3) acc[mt][nt] = mm_bf16(al[mt], bh[nt], acc[mt][nt]);
      }
  }

  if constexpr (EPI == 2) {
    // --- scores epilogue: tile is S^T [128 kv][128 q]; per-lane global Adj reads ---
    __syncthreads();                       // stage bufs dead; reuse LDS
    float* sred = (float*)lds;             // [2 wm][128 q]
    float* ssum = sred + 256;
    u16* pb = lds + 1024;                  // [128 q][136] u16
    float mfin[4];
#pragma unroll
    for (int nt = 0; nt < 4; nt++) {
      const int q_l = wn * 64 + nt * 16 + lr;
      const float* arow = Adj + (size_t)(nbase + q_l) * (size_t)M + mbase + wm * 64 + lk * 4;
      float4 a4[4];
#pragma unroll
      for (int mt = 0; mt < 4; mt++) a4[mt] = *(const float4*)(arow + mt * 16);
      float mx = -3.4e38f;
#pragma unroll
      for (int mt = 0; mt < 4; mt++)
#pragma unroll
        for (int r = 0; r < 4; r++) {
          float s = acc[mt][nt][r] * ((const float*)&a4[mt])[r] * scale;
          acc[mt][nt][r] = s;
          mx = fmaxf(mx, s);
        }
      mx = fmaxf(mx, __shfl_xor(mx, 16));
      mx = fmaxf(mx, __shfl_xor(mx, 32));
      if (lane < 16) sred[wm * 128 + wn * 64 + nt * 16 + lane] = mx;
    }
    __syncthreads();
#pragma unroll
    for (int nt = 0; nt < 4; nt++) {
      const int qi = wn * 64 + nt * 16 + lr;
      mfin[nt] = fmaxf(sred[qi], sred[128 + qi]);
    }
    if (wm == 0 && lane < 16) {
#pragma unroll
      for (int nt = 0; nt < 4; nt++)
        mC[(size_t)blockIdx.x * N + nbase + wn * 64 + nt * 16 + lane] = mfin[nt];
    }
#pragma unroll
    for (int nt = 0; nt < 4; nt++) {
      float sm = 0.f;
#pragma unroll
      for (int mt = 0; mt < 4; mt++)
#pragma unroll
        for (int r = 0; r < 4; r++) {
          float p = __expf(acc[mt][nt][r] - mfin[nt]);
          acc[mt][nt][r] = p;
          sm += p;
        }
      sm += __shfl_xor(sm, 16);
      sm += __shfl_xor(sm, 32);
      if (lane < 16) ssum[wm * 128 + wn * 64 + nt * 16 + lane] = sm;
    }
    __syncthreads();
    if (wm == 0 && lane < 16) {
#pragma unroll
      for (int nt = 0; nt < 4; nt++) {
        const int qi = wn * 64 + nt * 16 + lane;
        lC[(size_t)blockIdx.x * N + nbase + qi] = ssum[qi] + ssum[128 + qi];
      }
    }
#pragma unroll
    for (int nt = 0; nt < 4; nt++) {
      const int q_l = wn * 64 + nt * 16 + lr;
#pragma unroll
      for (int mt = 0; mt < 4; mt++) {
        const int kvo = wm * 64 + mt * 16 + lk * 4;
        u32 u0 = (u32)f2bf(acc[mt][nt][0]) | ((u32)f2bf(acc[mt][nt][1]) << 16);
        u32 u1 = (u32)f2bf(acc[mt][nt][2]) | ((u32)f2bf(acc[mt][nt][3]) << 16);
        *(uint2*)&pb[q_l * 136 + kvo] = make_uint2(u0, u1);
      }
    }
    __syncthreads();
    {
      u16* dst = Pout + (size_t)(nbase + srow) * (size_t)M + mbase + shalf * 64;
      const u16* srcp = &pb[srow * 136 + shalf * 64];
#pragma unroll
      for (int i = 0; i < 8; i++) ((uint4*)dst)[i] = ((const uint4*)srcp)[i];
    }
  } else {
    float* cfp = Cf;
    if constexpr (KSPLIT > 1) {
      if (blockIdx.z == 1) cfp = Cf1;
      else if (blockIdx.z == 2) cfp = Cf2;
    }
#pragma unroll
    for (int mt = 0; mt < 4; mt++)
#pragma unroll
      for (int nt = 0; nt < 4; nt++) {
        const int grow = mbase + wm * 64 + mt * 16 + lk * 4;
        const int gcol = nbase + wn * 64 + nt * 16 + lr;
#pragma unroll
        for (int r = 0; r < 4; r++) {
          float c = acc[mt][nt][r];
          size_t o = (size_t)(grow + r) * N + gcol;
          if constexpr (EPI == 0) {
            u16 h = f2bf(c);
            c0[o] = h;
            c1[o] = f2bf(c - bf2f(h));
          } else {
            cfp[o] = c;
          }
        }
      }
  }
}

// ---------------- softmax cross-chunk reduce ----------------

__global__ void k_reduce(const float* __restrict__ mC, const float* __restrict__ lC, float* __restrict__ F,
                         int NQ, int NC) {
  const int q = blockIdx.x * 256 + threadIdx.x;
  if (q >= NQ) return;
  float mf = -3.4e38f;
  for (int c = 0; c < NC; c++) mf = fmaxf(mf, mC[(size_t)c * NQ + q]);
  float L = 0.f;
  for (int c = 0; c < NC; c++) L += lC[(size_t)c * NQ + q] * __expf(mC[(size_t)c * NQ + q] - mf);
  const float inv = 1.0f / L;
  for (int c = 0; c < NC; c++) F[(size_t)c * NQ + q] = __expf(mC[(size_t)c * NQ + q] - mf) * inv;
}

// out += p1 + p2  (fp32, fixed order -> deterministic)
__global__ void k_sumout(float* __restrict__ out, const float* __restrict__ p1, const float* __restrict__ p2, int n4) {
  int i = blockIdx.x * 256 + threadIdx.x;
  if (i >= n4) return;
  float4 o = ((const float4*)out)[i];
  float4 a = ((const float4*)p1)[i];
  float4 b = ((const float4*)p2)[i];
  o.x += a.x + b.x; o.y += a.y + b.y; o.z += a.z + b.z; o.w += a.w + b.w;
  ((float4*)out)[i] = o;
}

// ---------------- launcher ----------------

extern "C" void kernel_launch(void* const* d_in, const int* in_sizes, int n_in,
                              void* d_out, int out_size, void* d_ws, size_t ws_size,
                              hipStream_t stream) {
  const float* H  = (const float*)d_in[0];
  const float* Aj = (const float*)d_in[1];
  const float* Wq = (const float*)d_in[2];
  const float* Wk = (const float*)d_in[3];
  const float* Wv = (const float*)d_in[4];
  float* out = (float*)d_out;
  const int NN = 8192, DD = 512;

  char* ws = (char*)d_ws;
  size_t off = 0;
  auto alloc = [&](size_t bytes) -> void* {
    void* p = ws + off;
    off += (bytes + 255) & ~(size_t)255;
    return p;
  };
  u16* Pbuf  = (u16*)alloc((size_t)NN * NN * 2);           // 128 MB
  u16* Hhi   = (u16*)alloc((size_t)NN * DD * 2);
  u16* Hlo   = (u16*)alloc((size_t)NN * DD * 2);
  u16* WThi  = (u16*)alloc((size_t)3 * DD * DD * 2);
  u16* WTlo  = (u16*)alloc((size_t)3 * DD * DD * 2);
  u16* PRhi  = (u16*)alloc((size_t)3 * NN * DD * 2);       // [HQ|HK|HV] hi
  u16* PRlo  = (u16*)alloc((size_t)3 * NN * DD * 2);
  u16* HVthi = (u16*)alloc((size_t)NN * DD * 2);
  float* mC  = (float*)alloc((size_t)64 * NN * 4);
  float* lC  = (float*)alloc((size_t)64 * NN * 4);
  float* Ft  = (float*)alloc((size_t)64 * NN * 4);
  if (off > ws_size) return;  // workspace too small -> visible failure

  u16* HQhi = PRhi;                 u16* HQlo = PRlo;
  u16* HKhi = PRhi + (size_t)NN*DD; u16* HKlo = PRlo + (size_t)NN*DD;
  u16* HVhi = PRhi + (size_t)2*NN*DD;

  // K-split partials for PV GEMM: alias the dead region (Hhi.. is dead by then)
  float* part1 = (float*)Hhi;
  float* part2 = (float*)((char*)Hhi + (size_t)NN * DD * 4);

  const float scl = 1.0f / sqrtf((float)DD);

  k_split<<<4096, 256, 0, stream>>>(H, Hhi, Hlo, NN * DD / 4);
  k_prepW<<<3072, 256, 0, stream>>>(Wq, Wk, Wv, WThi, WTlo);

  // fused Q/K/V projections: grid y = {w}*4 + {n-tile}
  dim3 gP(64, 12);
  gemm_bt<0, 3, 1, 1><<<gP, 256, 0, stream>>>(Hhi, Hlo, WThi, WTlo, NN, DD, DD,
                                              nullptr, nullptr, nullptr, PRhi, PRlo,
                                              nullptr, nullptr, nullptr, nullptr, nullptr, 0.f);

  dim3 gT(128, 8);
  k_transpose<<<gT, 256, 0, stream>>>(HVhi, HVthi, NN, DD);

  dim3 gS(64, 64);
  gemm_bt<2, 3, 0, 1><<<gS, 256, 0, stream>>>(HKhi, HKlo, HQhi, HQlo, NN, NN, DD,
                                              nullptr, nullptr, nullptr, nullptr, nullptr,
                                              Aj, mC, lC, Pbuf, nullptr, scl);

  k_reduce<<<32, 256, 0, stream>>>(mC, lC, Ft, NN, 64);

  // out = (P'*F) @ HVt^T, 1-pass (V-lo dropped), K split 3-way for occupancy
  dim3 gO(64, 4, 3);
  gemm_bt<3, 1, 0, 3><<<gO, 256, 0, stream>>>(Pbuf, nullptr, HVthi, nullptr, NN, DD, NN,
                                              out, part1, part2, nullptr, nullptr,
                                              nullptr, nullptr, nullptr, nullptr, Ft, 0.f);

  k_sumout<<<4096, 256, 0, stream>>>(out, part1, part2, NN * DD / 4);
}